// Round 3
// baseline (843.826 us; speedup 1.0000x reference)
//
#include <hip/hip_runtime.h>
#include <cstdint>
#include <cstddef>

// Round 3: read-ahead 8-phase 256x256 GEMM. Reads for phase p+1's MFMA are
// issued in phase p (before phase p's MFMA, no lgkmcnt(0) between) so the
// LDS-read drain overlaps MFMA execution. Ledger: stage(region) >= 2 phases
// after last read of region; buf-switch reads only after vm(8)+BAR.
// y = x_bf16 @ (w*bf16(scale))_bf16^T + bias  (x_dq == x exactly: pow2 scales)

typedef __attribute__((ext_vector_type(8))) __bf16 bf16x8;
typedef __attribute__((ext_vector_type(4))) float f32x4;

__device__ __forceinline__ unsigned short bf16rn(float f) {
  unsigned u = __builtin_bit_cast(unsigned, f);
  u = (u + 0x7FFFu + ((u >> 16) & 1u)) >> 16;
  return (unsigned short)u;
}
__device__ __forceinline__ float bf16tof(unsigned short h) {
  unsigned u = ((unsigned)h) << 16;
  return __builtin_bit_cast(float, u);
}
__device__ __forceinline__ void gload_lds16(const void* g, void* l) {
  __builtin_amdgcn_global_load_lds(
      (const __attribute__((address_space(1))) unsigned int*)g,
      (__attribute__((address_space(3))) unsigned int*)l, 16, 0, 0);
}

// ---------------- Phase A: fused prep (x->bf16, w*scale->bf16) -------------

__global__ __launch_bounds__(256) void k_prep(
    const float* __restrict__ x, const float* __restrict__ w,
    const float* __restrict__ sc, unsigned short* __restrict__ xb,
    unsigned short* __restrict__ wb, int K, int nblk, int blk,
    int n8x, int n8w) {
  int t = blockIdx.x * 256 + threadIdx.x;
  if (t < n8x) {
    const float4* p = (const float4*)x + (size_t)t * 2;
    float4 a = p[0], b = p[1];
    uint4 o;
    o.x = (unsigned)bf16rn(a.x) | ((unsigned)bf16rn(a.y) << 16);
    o.y = (unsigned)bf16rn(a.z) | ((unsigned)bf16rn(a.w) << 16);
    o.z = (unsigned)bf16rn(b.x) | ((unsigned)bf16rn(b.y) << 16);
    o.w = (unsigned)bf16rn(b.z) | ((unsigned)bf16rn(b.w) << 16);
    ((uint4*)xb)[t] = o;
  } else if (t - n8x < n8w) {
    int tw = t - n8x;
    size_t base = (size_t)tw * 8;
    int o_row = (int)(base / (size_t)K);
    int k = (int)(base % (size_t)K);
    float s = bf16tof(bf16rn(sc[(size_t)o_row * nblk + k / blk]));
    const float4* p = (const float4*)w + (size_t)tw * 2;
    float4 a = p[0], b = p[1];
    uint4 o;
    o.x = (unsigned)bf16rn(a.x * s) | ((unsigned)bf16rn(a.y * s) << 16);
    o.y = (unsigned)bf16rn(a.z * s) | ((unsigned)bf16rn(a.w * s) << 16);
    o.z = (unsigned)bf16rn(b.x * s) | ((unsigned)bf16rn(b.y * s) << 16);
    o.w = (unsigned)bf16rn(b.z * s) | ((unsigned)bf16rn(b.w * s) << 16);
    ((uint4*)wb)[tw] = o;
  }
}

// ---------------- Phase B: 256^2 read-ahead 8-phase GEMM -------------------
// C[M][N] = A[M][K]*B[N][K]^T + bias. 512 thr = 8 waves (2Mx4N).
// LDS 128 KiB: 2 bufs x (A[256][64] + B[256][64]) bf16, XOR-swizzled
// (byte ^= (row&7)<<4, inverse-applied on global source, rule 21).

#define BM 256
#define BN 256
#define BK 64

#define BAR() __builtin_amdgcn_s_barrier()
#define WAIT_VM(n) asm volatile("s_waitcnt vmcnt(" #n ")" ::: "memory")
#define SCHEDB() __builtin_amdgcn_sched_barrier(0)
#define PRIO(p) __builtin_amdgcn_s_setprio(p)

#define STG_A(buf, q, tile)                                               \
  gload_lds16(Ag + (size_t)(q) * 64 * Ks + (size_t)(tile) * BK,           \
              smem + (buf) * 65536 + (q) * 8192 + tid16)
#define STG_B(buf, q, tile)                                               \
  gload_lds16(Bg + (size_t)(q) * 64 * Ks + (size_t)(tile) * BK,           \
              smem + (buf) * 65536 + 32768 + (q) * 8192 + tid16)

#define READ_A(arr, buf, qm)                                              \
  _Pragma("unroll") for (int i_ = 0; i_ < 4; ++i_) {                      \
    arr[i_][0] = *(const bf16x8*)(smem + (buf) * 65536 +                  \
        (wr * 128 + (qm) * 64 + i_ * 16 + lr) * 128 + ko0);               \
    arr[i_][1] = *(const bf16x8*)(smem + (buf) * 65536 +                  \
        (wr * 128 + (qm) * 64 + i_ * 16 + lr) * 128 + ko1);               \
  }
#define READ_B(arr, buf, qn)                                              \
  _Pragma("unroll") for (int j_ = 0; j_ < 2; ++j_) {                      \
    arr[j_][0] = *(const bf16x8*)(smem + (buf) * 65536 + 32768 +          \
        (wc * 64 + (qn) * 32 + j_ * 16 + lr) * 128 + ko0);                \
    arr[j_][1] = *(const bf16x8*)(smem + (buf) * 65536 + 32768 +          \
        (wc * 64 + (qn) * 32 + j_ * 16 + lr) * 128 + ko1);                \
  }
#define MFMA_Q(qm, qn, aarr, barr)                                        \
  _Pragma("unroll") for (int kk_ = 0; kk_ < 2; ++kk_)                     \
  _Pragma("unroll") for (int i_ = 0; i_ < 4; ++i_)                        \
  _Pragma("unroll") for (int j_ = 0; j_ < 2; ++j_)                        \
    acc[(qm) * 4 + i_][(qn) * 2 + j_] =                                   \
        __builtin_amdgcn_mfma_f32_16x16x32_bf16(                          \
            aarr[i_][kk_], barr[j_][kk_],                                 \
            acc[(qm) * 4 + i_][(qn) * 2 + j_], 0, 0, 0);

__global__ __launch_bounds__(512, 2) void k_gemm256(
    const unsigned short* __restrict__ A, const unsigned short* __restrict__ B,
    const float* __restrict__ bias, float* __restrict__ C,
    int M, int N, int K) {
  extern __shared__ __align__(16) char smem[];

  const int nbn = N / BN;
  const int nwg = gridDim.x;
  int bid = blockIdx.x;
  int wg = bid;
  if ((nwg & 7) == 0) wg = (bid & 7) * (nwg >> 3) + (bid >> 3);  // T1
  const int m0 = (wg / nbn) * BM;
  const int n0 = (wg % nbn) * BN;

  const int tid = threadIdx.x;
  const int lane = tid & 63;
  const int wid = tid >> 6;
  const int wr = wid >> 2;
  const int wc = wid & 3;
  const int lr = lane & 15;
  const int ko0 = (((lane >> 4) * 16) ^ ((lane & 7) << 4));
  const int ko1 = ((64 | ((lane >> 4) * 16)) ^ ((lane & 7) << 4));
  const int tid16 = tid * 16;

  const int srow = tid >> 3;
  const int sgran = (tid & 7) ^ (srow & 7);  // inverse swizzle on source
  const size_t Ks = (size_t)K;
  const unsigned short* Ag = A + (size_t)(m0 + srow) * Ks + sgran * 8;
  const unsigned short* Bg = B + (size_t)(n0 + srow) * Ks + sgran * 8;

  f32x4 acc[8][4] = {};
  bf16x8 a0[4][2], a1[4][2], b0[2][2], b1[2][2];

  const int NT = K / BK;
  const int NITER = NT / 2;

  // prologue: t0 -> buf0 (8 loads), t1 -> buf1 (8 loads)
  STG_A(0, 0, 0); STG_A(0, 2, 0); STG_B(0, 0, 0); STG_B(0, 1, 0);
  STG_A(0, 1, 0); STG_A(0, 3, 0); STG_B(0, 2, 0); STG_B(0, 3, 0);
  STG_A(1, 0, 1); STG_A(1, 2, 1); STG_B(1, 0, 1); STG_B(1, 1, 1);
  STG_A(1, 1, 1); STG_A(1, 3, 1); STG_B(1, 2, 1); STG_B(1, 3, 1);
  WAIT_VM(8);  // t0 landed; t1's 8 in flight
  BAR(); SCHEDB();
  READ_A(a0, 0, 0); READ_B(b0, 0, 0);  // Q00(t0) operands (the "P7/P8-prev" reads)

  for (int it = 0; it < NITER; ++it) {
    const int t = 2 * it;
    const bool pf = (t + 2) < NT;  // stage tiles t+2 (buf0) and t+3 (buf1)
    // P1: reads b1.buf0 || MFMA Q00.buf0 (a0,b0)
    PRIO(1);
    READ_B(b1, 0, 1);
    MFMA_Q(0, 0, a0, b0);
    PRIO(0); BAR();
    // P2: stage A02(t+2); reads a1.buf0 || MFMA Q01.buf0 (a0,b1)
    if (pf) { STG_A(0, 0, t + 2); STG_A(0, 2, t + 2); }
    PRIO(1);
    READ_A(a1, 0, 1);
    MFMA_Q(0, 1, a0, b1);
    PRIO(0); BAR();
    // P3: stage B01(t+2); MFMA Q10.buf0 (a1,b0)
    if (pf) { STG_B(0, 0, t + 2); STG_B(0, 1, t + 2); }
    PRIO(1);
    MFMA_Q(1, 0, a1, b0);
    PRIO(0); BAR();
    // P4: stage A13,B23(t+2); vm(8): t+1 landed; reads a0,b0.buf1 || MFMA Q11.buf0
    if (pf) {
      STG_A(0, 1, t + 2); STG_A(0, 3, t + 2);
      STG_B(0, 2, t + 2); STG_B(0, 3, t + 2);
      WAIT_VM(8);
    } else {
      WAIT_VM(0);
    }
    BAR(); SCHEDB();
    PRIO(1);
    READ_A(a0, 1, 0); READ_B(b0, 1, 0);
    MFMA_Q(1, 1, a1, b1);
    PRIO(0); BAR();
    // P5: reads b1.buf1 || MFMA Q00.buf1 (a0,b0)
    PRIO(1);
    READ_B(b1, 1, 1);
    MFMA_Q(0, 0, a0, b0);
    PRIO(0); BAR();
    // P6: stage A02(t+3); reads a1.buf1 || MFMA Q01.buf1 (a0,b1)
    if (pf) { STG_A(1, 0, t + 3); STG_A(1, 2, t + 3); }
    PRIO(1);
    READ_A(a1, 1, 1);
    MFMA_Q(0, 1, a0, b1);
    PRIO(0); BAR();
    // P7: stage B01(t+3); MFMA Q10.buf1 (a1,b0)
    if (pf) { STG_B(1, 0, t + 3); STG_B(1, 1, t + 3); }
    PRIO(1);
    MFMA_Q(1, 0, a1, b0);
    PRIO(0); BAR();
    // P8: stage A13,B23(t+3); vm(8): t+2 landed; reads a0,b0.buf0(t+2) || MFMA Q11.buf1
    if (pf) {
      STG_A(1, 1, t + 3); STG_A(1, 3, t + 3);
      STG_B(1, 2, t + 3); STG_B(1, 3, t + 3);
      WAIT_VM(8);
      BAR(); SCHEDB();
      PRIO(1);
      READ_A(a0, 0, 0); READ_B(b0, 0, 0);
      MFMA_Q(1, 1, a1, b1);
      PRIO(0); BAR();
    } else {
      BAR();
      PRIO(1);
      MFMA_Q(1, 1, a1, b1);
      PRIO(0);
    }
  }

  // epilogue: frag (i,j) at (i*16, j*16); col=lane&15, row=(lane>>4)*4+r
  const int col0 = n0 + wc * 64 + (lane & 15);
  const int row0 = m0 + wr * 128 + ((lane >> 4) << 2);
#pragma unroll
  for (int j = 0; j < 4; ++j) {
    float bj = bias[col0 + j * 16];
#pragma unroll
    for (int i = 0; i < 8; ++i) {
#pragma unroll
      for (int r = 0; r < 4; ++r) {
        C[(size_t)(row0 + i * 16 + r) * N + (col0 + j * 16)] = acc[i][j][r] + bj;
      }
    }
  }
}

// ---------------- fallback (exact f32) ----------------

__global__ __launch_bounds__(256) void k_fallback(
    const float* __restrict__ x, const float* __restrict__ w,
    const float* __restrict__ sc, const float* __restrict__ bias,
    float* __restrict__ out, int T, int O, int K, int nblk, int blk) {
  long long idx = (long long)blockIdx.x * 256 + threadIdx.x;
  if (idx >= (long long)T * O) return;
  int row = (int)(idx / O), col = (int)(idx % O);
  const float* xr = x + (size_t)row * K;
  const float* wr = w + (size_t)col * K;
  const float* sr = sc + (size_t)col * nblk;
  float acc = 0.f;
  for (int b = 0; b < nblk; ++b) {
    float s = bf16tof(bf16rn(sr[b]));
    float part = 0.f;
    for (int k = 0; k < blk; k += 4) {
      float4 xa = *(const float4*)(xr + b * blk + k);
      float4 wa = *(const float4*)(wr + b * blk + k);
      part += xa.x * wa.x + xa.y * wa.y + xa.z * wa.z + xa.w * wa.w;
    }
    acc += part * s;
  }
  out[idx] = acc + bias[col];
}

extern "C" void kernel_launch(void* const* d_in, const int* in_sizes, int n_in,
                              void* d_out, int out_size, void* d_ws, size_t ws_size,
                              hipStream_t stream) {
  const float* x = (const float*)d_in[0];
  const float* w = (const float*)d_in[1];
  const float* sc = (const float*)d_in[2];
  const float* bias = (const float*)d_in[3];
  float* out = (float*)d_out;

  const int x_n = in_sizes[0];
  const int w_n = in_sizes[1];
  const int s_n = in_sizes[2];
  const int O = in_sizes[3];
  const int K = w_n / O;
  const int T = x_n / K;
  const int nblk = s_n / O;
  const int blk = K / nblk;

  const size_t need = (size_t)x_n * 2 + (size_t)w_n * 2;
  const bool tiled_ok = ws_size >= need && (K % (2 * BK)) == 0 &&
                        (T % BM) == 0 && (O % BN) == 0 && (blk % 8) == 0 &&
                        K >= 2 * BK;

  if (tiled_ok) {
    unsigned short* xb = (unsigned short*)d_ws;
    unsigned short* wb = xb + (size_t)x_n;
    int n8x = x_n / 8, n8w = w_n / 8;
    int nprep = n8x + n8w;
    k_prep<<<(nprep + 255) / 256, 256, 0, stream>>>(x, w, sc, xb, wb, K, nblk,
                                                    blk, n8x, n8w);
    hipFuncSetAttribute((const void*)k_gemm256,
                        hipFuncAttributeMaxDynamicSharedMemorySize, 131072);
    dim3 grid((T / BM) * (O / BN));
    k_gemm256<<<grid, 512, 131072, stream>>>(xb, wb, bias, out, T, O, K);
  } else {
    long long total = (long long)T * O;
    dim3 grid((unsigned)((total + 255) / 256));
    k_fallback<<<grid, 256, 0, stream>>>(x, w, sc, bias, out, T, O, K, nblk, blk);
  }
}

// Round 4
// 317.982 us; speedup vs baseline: 2.6537x; 2.6537x over previous
//
#include <hip/hip_runtime.h>
#include <cstdint>
#include <cstddef>

// Round 4: 256x256 GEMM, 32x32x16 MFMA, uniform 4-phase K-tiles,
// single-set A-prefetch (phase-local regs, no spill), bursty staging with
// vm(0)+BAR mid-P3. Sync skeleton = R2-proven (trailing BAR per phase).
// y = x_bf16 @ (w*bf16(scale))_bf16^T + bias  (x_dq == x exactly: pow2 scales)

typedef __attribute__((ext_vector_type(8))) __bf16 bf16x8;
typedef __attribute__((ext_vector_type(16))) float f32x16;

__device__ __forceinline__ unsigned short bf16rn(float f) {
  unsigned u = __builtin_bit_cast(unsigned, f);
  u = (u + 0x7FFFu + ((u >> 16) & 1u)) >> 16;
  return (unsigned short)u;
}
__device__ __forceinline__ float bf16tof(unsigned short h) {
  unsigned u = ((unsigned)h) << 16;
  return __builtin_bit_cast(float, u);
}
__device__ __forceinline__ void gload_lds16(const void* g, void* l) {
  __builtin_amdgcn_global_load_lds(
      (const __attribute__((address_space(1))) unsigned int*)g,
      (__attribute__((address_space(3))) unsigned int*)l, 16, 0, 0);
}

// ---------------- Phase A: fused prep (x->bf16, w*scale->bf16) -------------

__global__ __launch_bounds__(256) void k_prep(
    const float* __restrict__ x, const float* __restrict__ w,
    const float* __restrict__ sc, unsigned short* __restrict__ xb,
    unsigned short* __restrict__ wb, int K, int nblk, int blk,
    int n8x, int n8w) {
  int t = blockIdx.x * 256 + threadIdx.x;
  if (t < n8x) {
    const float4* p = (const float4*)x + (size_t)t * 2;
    float4 a = p[0], b = p[1];
    uint4 o;
    o.x = (unsigned)bf16rn(a.x) | ((unsigned)bf16rn(a.y) << 16);
    o.y = (unsigned)bf16rn(a.z) | ((unsigned)bf16rn(a.w) << 16);
    o.z = (unsigned)bf16rn(b.x) | ((unsigned)bf16rn(b.y) << 16);
    o.w = (unsigned)bf16rn(b.z) | ((unsigned)bf16rn(b.w) << 16);
    ((uint4*)xb)[t] = o;
  } else if (t - n8x < n8w) {
    int tw = t - n8x;
    size_t base = (size_t)tw * 8;
    int o_row = (int)(base / (size_t)K);
    int k = (int)(base % (size_t)K);
    float s = bf16tof(bf16rn(sc[(size_t)o_row * nblk + k / blk]));
    const float4* p = (const float4*)w + (size_t)tw * 2;
    float4 a = p[0], b = p[1];
    uint4 o;
    o.x = (unsigned)bf16rn(a.x * s) | ((unsigned)bf16rn(a.y * s) << 16);
    o.y = (unsigned)bf16rn(a.z * s) | ((unsigned)bf16rn(a.w * s) << 16);
    o.z = (unsigned)bf16rn(b.x * s) | ((unsigned)bf16rn(b.y * s) << 16);
    o.w = (unsigned)bf16rn(b.z * s) | ((unsigned)bf16rn(b.w * s) << 16);
    ((uint4*)wb)[tw] = o;
  }
}

// ---------------- Phase B: 256^2 GEMM, 32x32x16 -----------------
// C[M][N]=A[M][K]*B[N][K]^T + bias. 512 thr = 8 waves (2Mx4N), per-wave
// 128x64 out = 4x2 frags of 32x32. LDS: 2 bufs x (A 32KB + B 32KB) = 128KB.
// XOR swizzle byte ^= (row&7)<<4 (inverse-applied on global src, rule 21).

#define BM 256
#define BN 256
#define BK 64

#define BAR() __builtin_amdgcn_s_barrier()
#define WAIT_VM0() asm volatile("s_waitcnt vmcnt(0)" ::: "memory")
#define SCHEDB() __builtin_amdgcn_sched_barrier(0)
#define PRIO(p) __builtin_amdgcn_s_setprio(p)

// stage full tile tt (A+B, 8 quarter-loads) into buffer bi
#define STAGE8(bi, tt)                                                     \
  do {                                                                     \
    _Pragma("unroll") for (int q_ = 0; q_ < 4; ++q_)                       \
        gload_lds16(Ag + (size_t)q_ * 64 * Ks + (size_t)(tt) * BK,         \
                    smem + (bi) * 65536 + q_ * 8192 + tid16);              \
    _Pragma("unroll") for (int q_ = 0; q_ < 4; ++q_)                       \
        gload_lds16(Bg + (size_t)q_ * 64 * Ks + (size_t)(tt) * BK,         \
                    smem + (bi) * 65536 + 32768 + q_ * 8192 + tid16);      \
  } while (0)

// A frag (32x32x16): lane -> row = base + l31, k = kk*16 + (lane>>5)*8 + j
#define READ_A32(dst, bi, kkv)                                             \
  _Pragma("unroll") for (int mb_ = 0; mb_ < 4; ++mb_) {                    \
    dst[mb_] = *(const bf16x8*)(smem + (bi) * 65536 +                      \
        (wr * 128 + mb_ * 32 + l31) * 128 +                                \
        ((((kkv) * 32) + khi16) ^ ((l31 & 7) << 4)));                      \
  }
#define READ_B32(dst, bi, kkv)                                             \
  _Pragma("unroll") for (int nb_ = 0; nb_ < 2; ++nb_) {                    \
    dst[nb_] = *(const bf16x8*)(smem + (bi) * 65536 + 32768 +              \
        (wc * 64 + nb_ * 32 + l31) * 128 +                                 \
        ((((kkv) * 32) + khi16) ^ ((l31 & 7) << 4)));                      \
  }
#define MFMA8(aset, bset)                                                  \
  _Pragma("unroll") for (int mb_ = 0; mb_ < 4; ++mb_)                      \
  _Pragma("unroll") for (int nb_ = 0; nb_ < 2; ++nb_)                      \
      acc[mb_][nb_] = __builtin_amdgcn_mfma_f32_32x32x16_bf16(             \
          aset[mb_], bset[nb_], acc[mb_][nb_], 0, 0, 0);

__global__ __launch_bounds__(512, 2) void k_gemm256(
    const unsigned short* __restrict__ A, const unsigned short* __restrict__ B,
    const float* __restrict__ bias, float* __restrict__ C,
    int M, int N, int K) {
  extern __shared__ __align__(16) char smem[];

  const int nbn = N / BN;
  const int nwg = gridDim.x;
  int bid = blockIdx.x;
  int wg = bid;
  if ((nwg & 7) == 0) wg = (bid & 7) * (nwg >> 3) + (bid >> 3);  // T1
  const int m0 = (wg / nbn) * BM;
  const int n0 = (wg % nbn) * BN;

  const int tid = threadIdx.x;
  const int lane = tid & 63;
  const int wid = tid >> 6;
  const int wr = wid >> 2;   // 0..1 -> 128-row half
  const int wc = wid & 3;    // 0..3 -> 64-col group
  const int l31 = lane & 31;
  const int khi16 = (lane >> 5) * 16;  // byte offset of lane's k-octet
  const int tid16 = tid * 16;

  const int srow = tid >> 3;                 // 0..63 within quarter
  const int sgran = (tid & 7) ^ (srow & 7);  // inverse swizzle on source
  const size_t Ks = (size_t)K;
  const unsigned short* Ag = A + (size_t)(m0 + srow) * Ks + sgran * 8;
  const unsigned short* Bg = B + (size_t)(n0 + srow) * Ks + sgran * 8;

  f32x16 acc[4][2] = {};
  bf16x8 aset0[4], aset1[4], bset[2];

  const int NT = K / BK;     // even (K % 128 == 0 guaranteed by launcher)
  const int NITER = NT / 2;

  // prologue: stage t0 -> buf0, drain, first A-prefetch (kk0)
  STAGE8(0, 0);
  WAIT_VM0();
  BAR(); SCHEDB();
  READ_A32(aset0, 0, 0);

  for (int it = 0; it < NITER; ++it) {
    const int m = 2 * it;
#pragma unroll
    for (int half = 0; half < 2; ++half) {
      const int cur = half;            // tile m+half lives in buf(half)
      const int oth = half ^ 1;
      const int tnext = m + half + 1;  // staged this iter-half into buf(oth)
      const bool hn = tnext < NT;
      // P0: stage next tile; B(kk0); prefetch A(kk1); MFMA(set0)
      if (hn) STAGE8(oth, tnext);
      READ_B32(bset, cur, 0);
      READ_A32(aset1, cur, 1);
      PRIO(1); MFMA8(aset0, bset); PRIO(0);
      BAR();
      // P1: B(kk1); prefetch A(kk2); MFMA(set1)
      READ_B32(bset, cur, 1);
      READ_A32(aset0, cur, 2);
      PRIO(1); MFMA8(aset1, bset); PRIO(0);
      BAR();
      // P2: B(kk2); prefetch A(kk3); MFMA(set0)
      READ_B32(bset, cur, 2);
      READ_A32(aset1, cur, 3);
      PRIO(1); MFMA8(aset0, bset); PRIO(0);
      BAR();
      // P3: B(kk3); vm(0)+BAR (next tile landed); prefetch A(kk0,next); MFMA(set1)
      READ_B32(bset, cur, 3);
      if (hn) {
        WAIT_VM0();
        BAR(); SCHEDB();
        READ_A32(aset0, oth, 0);
      }
      PRIO(1); MFMA8(aset1, bset); PRIO(0);
      BAR();
    }
  }

  // epilogue: 32x32 C/D: col = lane&31, row = (reg&3) + 8*(reg>>2) + 4*(lane>>5)
  const int rbase = m0 + wr * 128 + ((lane >> 5) << 2);
  const int cbase = n0 + wc * 64 + l31;
#pragma unroll
  for (int nb = 0; nb < 2; ++nb) {
    float bj = bias[cbase + nb * 32];
#pragma unroll
    for (int mb = 0; mb < 4; ++mb) {
#pragma unroll
      for (int r = 0; r < 16; ++r) {
        int row = rbase + mb * 32 + (r & 3) + 8 * (r >> 2);
        C[(size_t)row * N + (cbase + nb * 32)] = acc[mb][nb][r] + bj;
      }
    }
  }
}

// ---------------- fallback (exact f32) ----------------

__global__ __launch_bounds__(256) void k_fallback(
    const float* __restrict__ x, const float* __restrict__ w,
    const float* __restrict__ sc, const float* __restrict__ bias,
    float* __restrict__ out, int T, int O, int K, int nblk, int blk) {
  long long idx = (long long)blockIdx.x * 256 + threadIdx.x;
  if (idx >= (long long)T * O) return;
  int row = (int)(idx / O), col = (int)(idx % O);
  const float* xr = x + (size_t)row * K;
  const float* wr = w + (size_t)col * K;
  const float* sr = sc + (size_t)col * nblk;
  float acc = 0.f;
  for (int b = 0; b < nblk; ++b) {
    float s = bf16tof(bf16rn(sr[b]));
    float part = 0.f;
    for (int k = 0; k < blk; k += 4) {
      float4 xa = *(const float4*)(xr + b * blk + k);
      float4 wa = *(const float4*)(wr + b * blk + k);
      part += xa.x * wa.x + xa.y * wa.y + xa.z * wa.z + xa.w * wa.w;
    }
    acc += part * s;
  }
  out[idx] = acc + bias[col];
}

extern "C" void kernel_launch(void* const* d_in, const int* in_sizes, int n_in,
                              void* d_out, int out_size, void* d_ws, size_t ws_size,
                              hipStream_t stream) {
  const float* x = (const float*)d_in[0];
  const float* w = (const float*)d_in[1];
  const float* sc = (const float*)d_in[2];
  const float* bias = (const float*)d_in[3];
  float* out = (float*)d_out;

  const int x_n = in_sizes[0];
  const int w_n = in_sizes[1];
  const int s_n = in_sizes[2];
  const int O = in_sizes[3];
  const int K = w_n / O;
  const int T = x_n / K;
  const int nblk = s_n / O;
  const int blk = K / nblk;

  const size_t need = (size_t)x_n * 2 + (size_t)w_n * 2;
  const bool tiled_ok = ws_size >= need && (K % (2 * BK)) == 0 &&
                        (T % BM) == 0 && (O % BN) == 0 && (blk % 8) == 0;

  if (tiled_ok) {
    unsigned short* xb = (unsigned short*)d_ws;
    unsigned short* wb = xb + (size_t)x_n;
    int n8x = x_n / 8, n8w = w_n / 8;
    int nprep = n8x + n8w;
    k_prep<<<(nprep + 255) / 256, 256, 0, stream>>>(x, w, sc, xb, wb, K, nblk,
                                                    blk, n8x, n8w);
    hipFuncSetAttribute((const void*)k_gemm256,
                        hipFuncAttributeMaxDynamicSharedMemorySize, 131072);
    dim3 grid((T / BM) * (O / BN));
    k_gemm256<<<grid, 512, 131072, stream>>>(xb, wb, bias, out, T, O, K);
  } else {
    long long total = (long long)T * O;
    dim3 grid((unsigned)((total + 255) / 256));
    k_fallback<<<grid, 256, 0, stream>>>(x, w, sc, bias, out, T, O, K, nblk, blk);
  }
}

// Round 5
// 276.898 us; speedup vs baseline: 3.0474x; 1.1484x over previous
//
#include <hip/hip_runtime.h>
#include <cstdint>
#include <cstddef>

// Round 5: R2-proven 8-phase 256x256 skeleton, minus forced lgkm full-drains
// (compiler emits fine-grained lgkmcnt so lead MFMAs overlap read drains),
// 8 barriers/iter (vm-guard folded into trailing BAR), row-burst epilogue.
// WAR ledger: every ds_read is consumed by an in-phase MFMA => returned
// before trailing BAR => staging >=1 barrier later is safe.
// y = x_bf16 @ (w*bf16(scale))_bf16^T + bias  (x_dq == x exactly: pow2 scales)

typedef __attribute__((ext_vector_type(8))) __bf16 bf16x8;
typedef __attribute__((ext_vector_type(4))) float f32x4;

__device__ __forceinline__ unsigned short bf16rn(float f) {
  unsigned u = __builtin_bit_cast(unsigned, f);
  u = (u + 0x7FFFu + ((u >> 16) & 1u)) >> 16;
  return (unsigned short)u;
}
__device__ __forceinline__ float bf16tof(unsigned short h) {
  unsigned u = ((unsigned)h) << 16;
  return __builtin_bit_cast(float, u);
}
__device__ __forceinline__ void gload_lds16(const void* g, void* l) {
  __builtin_amdgcn_global_load_lds(
      (const __attribute__((address_space(1))) unsigned int*)g,
      (__attribute__((address_space(3))) unsigned int*)l, 16, 0, 0);
}

// ---------------- Phase A: fused prep (x->bf16, w*scale->bf16) -------------

__global__ __launch_bounds__(256) void k_prep(
    const float* __restrict__ x, const float* __restrict__ w,
    const float* __restrict__ sc, unsigned short* __restrict__ xb,
    unsigned short* __restrict__ wb, int K, int nblk, int blk,
    int n8x, int n8w) {
  int t = blockIdx.x * 256 + threadIdx.x;
  if (t < n8x) {
    const float4* p = (const float4*)x + (size_t)t * 2;
    float4 a = p[0], b = p[1];
    uint4 o;
    o.x = (unsigned)bf16rn(a.x) | ((unsigned)bf16rn(a.y) << 16);
    o.y = (unsigned)bf16rn(a.z) | ((unsigned)bf16rn(a.w) << 16);
    o.z = (unsigned)bf16rn(b.x) | ((unsigned)bf16rn(b.y) << 16);
    o.w = (unsigned)bf16rn(b.z) | ((unsigned)bf16rn(b.w) << 16);
    ((uint4*)xb)[t] = o;
  } else if (t - n8x < n8w) {
    int tw = t - n8x;
    size_t base = (size_t)tw * 8;
    int o_row = (int)(base / (size_t)K);
    int k = (int)(base % (size_t)K);
    float s = bf16tof(bf16rn(sc[(size_t)o_row * nblk + k / blk]));
    const float4* p = (const float4*)w + (size_t)tw * 2;
    float4 a = p[0], b = p[1];
    uint4 o;
    o.x = (unsigned)bf16rn(a.x * s) | ((unsigned)bf16rn(a.y * s) << 16);
    o.y = (unsigned)bf16rn(a.z * s) | ((unsigned)bf16rn(a.w * s) << 16);
    o.z = (unsigned)bf16rn(b.x * s) | ((unsigned)bf16rn(b.y * s) << 16);
    o.w = (unsigned)bf16rn(b.z * s) | ((unsigned)bf16rn(b.w * s) << 16);
    ((uint4*)wb)[tw] = o;
  }
}

// ---------------- Phase B: 256^2 8-phase GEMM ----------------
// C[M][N] = A[M][K]*B[N][K]^T + bias. 512 thr = 8 waves (2Mx4N).
// LDS 128 KiB: 2 bufs x (A[256][64] + B[256][64]) bf16, XOR-swizzled
// (byte ^= (row&7)<<4, inverse-applied on global source, rule 21).

#define BM 256
#define BN 256
#define BK 64

#define BARF()                                  \
  do {                                          \
    __builtin_amdgcn_s_barrier();               \
    asm volatile("" ::: "memory");              \
    __builtin_amdgcn_sched_barrier(0);          \
  } while (0)
#define WAIT_VM(n) asm volatile("s_waitcnt vmcnt(" #n ")" ::: "memory")
#define PRIO(p) __builtin_amdgcn_s_setprio(p)

#define STG_A(buf, q, tile)                                               \
  gload_lds16(Ag + (size_t)(q) * 64 * Ks + (size_t)(tile) * BK,           \
              smem + (buf) * 65536 + (q) * 8192 + tid16)
#define STG_B(buf, q, tile)                                               \
  gload_lds16(Bg + (size_t)(q) * 64 * Ks + (size_t)(tile) * BK,           \
              smem + (buf) * 65536 + 32768 + (q) * 8192 + tid16)

#define READ_A(arr, buf, qm)                                              \
  _Pragma("unroll") for (int i_ = 0; i_ < 4; ++i_) {                      \
    arr[i_][0] = *(const bf16x8*)(smem + (buf) * 65536 +                  \
        (wr * 128 + (qm) * 64 + i_ * 16 + lr) * 128 + ko0);               \
    arr[i_][1] = *(const bf16x8*)(smem + (buf) * 65536 +                  \
        (wr * 128 + (qm) * 64 + i_ * 16 + lr) * 128 + ko1);               \
  }
#define READ_B(arr, buf, qn)                                              \
  _Pragma("unroll") for (int j_ = 0; j_ < 2; ++j_) {                      \
    arr[j_][0] = *(const bf16x8*)(smem + (buf) * 65536 + 32768 +          \
        (wc * 64 + (qn) * 32 + j_ * 16 + lr) * 128 + ko0);                \
    arr[j_][1] = *(const bf16x8*)(smem + (buf) * 65536 + 32768 +          \
        (wc * 64 + (qn) * 32 + j_ * 16 + lr) * 128 + ko1);                \
  }
#define MFMA_Q(qm, qn, aarr, barr)                                        \
  _Pragma("unroll") for (int kk_ = 0; kk_ < 2; ++kk_)                     \
  _Pragma("unroll") for (int i_ = 0; i_ < 4; ++i_)                        \
  _Pragma("unroll") for (int j_ = 0; j_ < 2; ++j_)                        \
    acc[(qm) * 4 + i_][(qn) * 2 + j_] =                                   \
        __builtin_amdgcn_mfma_f32_16x16x32_bf16(                          \
            aarr[i_][kk_], barr[j_][kk_],                                 \
            acc[(qm) * 4 + i_][(qn) * 2 + j_], 0, 0, 0);

__global__ __launch_bounds__(512, 2) void k_gemm256(
    const unsigned short* __restrict__ A, const unsigned short* __restrict__ B,
    const float* __restrict__ bias, float* __restrict__ C,
    int M, int N, int K) {
  extern __shared__ __align__(16) char smem[];

  const int nbn = N / BN;
  const int nwg = gridDim.x;
  int bid = blockIdx.x;
  int wg = bid;
  if ((nwg & 7) == 0) wg = (bid & 7) * (nwg >> 3) + (bid >> 3);  // T1
  const int m0 = (wg / nbn) * BM;
  const int n0 = (wg % nbn) * BN;

  const int tid = threadIdx.x;
  const int lane = tid & 63;
  const int wid = tid >> 6;
  const int wr = wid >> 2;
  const int wc = wid & 3;
  const int lr = lane & 15;
  const int ko0 = (((lane >> 4) * 16) ^ ((lane & 7) << 4));
  const int ko1 = ((64 | ((lane >> 4) * 16)) ^ ((lane & 7) << 4));
  const int tid16 = tid * 16;

  const int srow = tid >> 3;
  const int sgran = (tid & 7) ^ (srow & 7);  // inverse swizzle on source
  const size_t Ks = (size_t)K;
  const unsigned short* Ag = A + (size_t)(m0 + srow) * Ks + sgran * 8;
  const unsigned short* Bg = B + (size_t)(n0 + srow) * Ks + sgran * 8;

  f32x4 acc[8][4] = {};
  bf16x8 a0[4][2], a1[4][2], b0[2][2], b1[2][2];

  const int NT = K / BK;
  const int NITER = NT / 2;

  // prologue: t0 -> buf0 (8 loads), t1 -> buf1 first 6
  STG_A(0, 0, 0); STG_A(0, 2, 0); STG_B(0, 0, 0); STG_B(0, 1, 0);
  STG_A(0, 1, 0); STG_A(0, 3, 0); STG_B(0, 2, 0); STG_B(0, 3, 0);
  STG_A(1, 0, 1); STG_A(1, 2, 1); STG_B(1, 0, 1); STG_B(1, 1, 1);
  STG_A(1, 1, 1); STG_A(1, 3, 1);
  WAIT_VM(6);  // t0 landed; t1's 6 in flight
  BARF();

  for (int it = 0; it < NITER; ++it) {
    const int t = 2 * it;
    const bool pf = (t + 2) < NT;
    // P1: reads a0,b0(buf0); stage B23(t+1)->buf1; MFMA Q00
    READ_A(a0, 0, 0); READ_B(b0, 0, 0);
    STG_B(1, 2, t + 1); STG_B(1, 3, t + 1);
    PRIO(1); MFMA_Q(0, 0, a0, b0); PRIO(0);
    BARF();
    // P2: reads b1(buf0); stage A02(t+2)->buf0 (A{0,2} last read P1); MFMA Q01
    READ_B(b1, 0, 1);
    if (pf) { STG_A(0, 0, t + 2); STG_A(0, 2, t + 2); }
    PRIO(1); MFMA_Q(0, 1, a0, b1); PRIO(0);
    BARF();
    // P3: reads a1(buf0); stage B01(t+2) (B last read P2); MFMA Q10
    READ_A(a1, 0, 1);
    if (pf) { STG_B(0, 0, t + 2); STG_B(0, 1, t + 2); }
    PRIO(1); MFMA_Q(1, 0, a1, b0); PRIO(0);
    BARF();
    // P4: stage A13(t+2) (A{1,3} last read P3); MFMA Q11; vm: t+1 landed
    if (pf) { STG_A(0, 1, t + 2); STG_A(0, 3, t + 2); }
    PRIO(1); MFMA_Q(1, 1, a1, b1); PRIO(0);
    if (pf) { WAIT_VM(6); } else { WAIT_VM(0); }
    BARF();
    // P5: reads a0,b0(buf1,t+1); stage B23(t+2); MFMA Q00
    READ_A(a0, 1, 0); READ_B(b0, 1, 0);
    if (pf) { STG_B(0, 2, t + 2); STG_B(0, 3, t + 2); }
    PRIO(1); MFMA_Q(0, 0, a0, b0); PRIO(0);
    BARF();
    // P6: reads b1(buf1); stage A02(t+3)->buf1; MFMA Q01
    READ_B(b1, 1, 1);
    if (pf) { STG_A(1, 0, t + 3); STG_A(1, 2, t + 3); }
    PRIO(1); MFMA_Q(0, 1, a0, b1); PRIO(0);
    BARF();
    // P7: reads a1(buf1); stage B01(t+3); MFMA Q10
    READ_A(a1, 1, 1);
    if (pf) { STG_B(1, 0, t + 3); STG_B(1, 1, t + 3); }
    PRIO(1); MFMA_Q(1, 0, a1, b0); PRIO(0);
    BARF();
    // P8: stage A13(t+3); MFMA Q11; vm: t+2 landed
    if (pf) { STG_A(1, 1, t + 3); STG_A(1, 3, t + 3); }
    PRIO(1); MFMA_Q(1, 1, a1, b1); PRIO(0);
    if (pf) { WAIT_VM(6); }
    BARF();
  }

  // epilogue: row-burst order; col=lane&15, row=(lane>>4)*4+r per frag
  const int col0 = n0 + wc * 64 + (lane & 15);
  const int row0 = m0 + wr * 128 + ((lane >> 4) << 2);
  float bj[4];
#pragma unroll
  for (int j = 0; j < 4; ++j) bj[j] = bias[col0 + j * 16];
#pragma unroll
  for (int i = 0; i < 8; ++i) {
#pragma unroll
    for (int r = 0; r < 4; ++r) {
      const size_t ro = (size_t)(row0 + i * 16 + r) * N;
#pragma unroll
      for (int j = 0; j < 4; ++j) {
        C[ro + col0 + j * 16] = acc[i][j][r] + bj[j];
      }
    }
  }
}

// ---------------- fallback (exact f32) ----------------

__global__ __launch_bounds__(256) void k_fallback(
    const float* __restrict__ x, const float* __restrict__ w,
    const float* __restrict__ sc, const float* __restrict__ bias,
    float* __restrict__ out, int T, int O, int K, int nblk, int blk) {
  long long idx = (long long)blockIdx.x * 256 + threadIdx.x;
  if (idx >= (long long)T * O) return;
  int row = (int)(idx / O), col = (int)(idx % O);
  const float* xr = x + (size_t)row * K;
  const float* wr = w + (size_t)col * K;
  const float* sr = sc + (size_t)col * nblk;
  float acc = 0.f;
  for (int b = 0; b < nblk; ++b) {
    float s = bf16tof(bf16rn(sr[b]));
    float part = 0.f;
    for (int k = 0; k < blk; k += 4) {
      float4 xa = *(const float4*)(xr + b * blk + k);
      float4 wa = *(const float4*)(wr + b * blk + k);
      part += xa.x * wa.x + xa.y * wa.y + xa.z * wa.z + xa.w * wa.w;
    }
    acc += part * s;
  }
  out[idx] = acc + bias[col];
}

extern "C" void kernel_launch(void* const* d_in, const int* in_sizes, int n_in,
                              void* d_out, int out_size, void* d_ws, size_t ws_size,
                              hipStream_t stream) {
  const float* x = (const float*)d_in[0];
  const float* w = (const float*)d_in[1];
  const float* sc = (const float*)d_in[2];
  const float* bias = (const float*)d_in[3];
  float* out = (float*)d_out;

  const int x_n = in_sizes[0];
  const int w_n = in_sizes[1];
  const int s_n = in_sizes[2];
  const int O = in_sizes[3];
  const int K = w_n / O;
  const int T = x_n / K;
  const int nblk = s_n / O;
  const int blk = K / nblk;

  const size_t need = (size_t)x_n * 2 + (size_t)w_n * 2;
  const bool tiled_ok = ws_size >= need && (K % (2 * BK)) == 0 &&
                        (T % BM) == 0 && (O % BN) == 0 && (blk % 8) == 0 &&
                        K >= 2 * BK;

  if (tiled_ok) {
    unsigned short* xb = (unsigned short*)d_ws;
    unsigned short* wb = xb + (size_t)x_n;
    int n8x = x_n / 8, n8w = w_n / 8;
    int nprep = n8x + n8w;
    k_prep<<<(nprep + 255) / 256, 256, 0, stream>>>(x, w, sc, xb, wb, K, nblk,
                                                    blk, n8x, n8w);
    hipFuncSetAttribute((const void*)k_gemm256,
                        hipFuncAttributeMaxDynamicSharedMemorySize, 131072);
    dim3 grid((T / BM) * (O / BN));
    k_gemm256<<<grid, 512, 131072, stream>>>(xb, wb, bias, out, T, O, K);
  } else {
    long long total = (long long)T * O;
    dim3 grid((unsigned)((total + 255) / 256));
    k_fallback<<<grid, 256, 0, stream>>>(x, w, sc, bias, out, T, O, K, nblk, blk);
  }
}